// Round 11
// baseline (1334.023 us; speedup 1.0000x reference)
//
#include <hip/hip_runtime.h>
#include <math.h>

#define N_ROWS 65536
#define CB 1024
#define SPLITS 4
#define JS (CB / SPLITS)   // 256 codebook entries per split

typedef float v4f __attribute__((ext_vector_type(4)));

// ---------------------------------------------------------------------------
// Exact emulation of numpy's pairwise_sum for n=64 fp32 (AVX-512 path).
// fp contract OFF so the squares are not fused into the adds.
// ---------------------------------------------------------------------------
__device__ __forceinline__ float tree_sum64_sq(const float* x) {
#pragma clang fp contract(off)
    float sq[64];
#pragma unroll
    for (int i = 0; i < 64; ++i) sq[i] = x[i] * x[i];
    float s[16];
#pragma unroll
    for (int l = 0; l < 16; ++l) s[l] = (sq[l] + sq[l + 16]) + (sq[l + 32] + sq[l + 48]);
    float t[8];
#pragma unroll
    for (int l = 0; l < 8; ++l) t[l] = s[l] + s[l + 8];
    float u[4];
#pragma unroll
    for (int l = 0; l < 4; ++l) u[l] = t[l] + t[l + 4];
    float v0 = u[0] + u[2];
    float v1 = u[1] + u[3];
    return v0 + v1;
}

// sorted-triple insert, strict < (ties keep earlier-inserted = lower index,
// matching jax.lax.top_k stable tie-breaking when fed in ascending index order)
__device__ __forceinline__ void top3_insert(float d, int j,
                                            float& v0, float& v1, float& v2,
                                            int& i0, int& i1, int& i2) {
    bool b0 = d < v0, b1 = d < v1, b2 = d < v2;
    v2 = b1 ? v1 : (b2 ? d : v2);
    i2 = b1 ? i1 : (b2 ? j : i2);
    v1 = b0 ? v0 : (b1 ? d : v1);
    i1 = b0 ? i0 : (b1 ? j : i1);
    v0 = b0 ? d : v0;
    i0 = b0 ? j : i0;
}

__device__ __forceinline__ void load_row(const float* __restrict__ z, int row,
                                         float* zr) {
    const float4* z4 = (const float4*)(z + (size_t)row * 64);
#pragma unroll
    for (int k = 0; k < 16; ++k) {
        float4 v = z4[k];
        zr[4 * k] = v.x; zr[4 * k + 1] = v.y; zr[4 * k + 2] = v.z; zr[4 * k + 3] = v.w;
    }
}

// ---------------------------------------------------------------------------
// B[j] = np.sum(emb[j]**2) (exact tree emulation) + zero hist/lossAcc.
// ---------------------------------------------------------------------------
__global__ __launch_bounds__(256) void prep_kernel(const float* __restrict__ emb,
                                                   float* __restrict__ B,
                                                   int* __restrict__ hist,
                                                   float* __restrict__ lossAcc) {
    int j = blockIdx.x * 256 + threadIdx.x;
    if (j >= CB) return;
    float e[64];
    load_row(emb, j, e);
    B[j] = tree_sum64_sq(e);
    hist[j] = 0;
    if (j == 0) *lossAcc = 0.0f;
}

// ---------------------------------------------------------------------------
// Per-row epilogue (identical FP ops to all passing rounds), factored so the
// caller can select the compile-time zr set (no runtime register indexing).
// ---------------------------------------------------------------------------
__device__ __forceinline__ float epilogue_row(const float* zr, int row,
                                              int j0, int j1, int j2,
                                              const float* __restrict__ emb,
                                              float* __restrict__ out0,
                                              float* __restrict__ out3f,
                                              float* __restrict__ out4,
                                              int* __restrict__ hist) {
    // one-hot "one" positions (zeros laid down by the prior memset)
    size_t sb = (size_t)row * 3072;
    out3f[sb + j0]        = 1.0f;
    out3f[sb + 1024 + j1] = 1.0f;
    out3f[sb + 2048 + j2] = 1.0f;

    const float4* e0q = (const float4*)(emb + (size_t)j0 * 64);
    const float4* e1q = (const float4*)(emb + (size_t)j1 * 64);
    const float4* e2q = (const float4*)(emb + (size_t)j2 * 64);
    v4f* o4 = (v4f*)(out0 + (size_t)row * 64);

    float lsum = 0.0f;
#pragma unroll
    for (int k4 = 0; k4 < 16; ++k4) {
        float4 a = e0q[k4], b = e1q[k4], cc = e2q[k4];
        float zx = zr[4 * k4], zy = zr[4 * k4 + 1];
        float zz = zr[4 * k4 + 2], zw = zr[4 * k4 + 3];
        v4f st;
        float zq, df;
        zq = ((a.x + b.x) + cc.x) / 3.0f; df = zq - zx; st.x = zx + df; lsum = fmaf(df, df, lsum);
        zq = ((a.y + b.y) + cc.y) / 3.0f; df = zq - zy; st.y = zy + df; lsum = fmaf(df, df, lsum);
        zq = ((a.z + b.z) + cc.z) / 3.0f; df = zq - zz; st.z = zz + df; lsum = fmaf(df, df, lsum);
        zq = ((a.w + b.w) + cc.w) / 3.0f; df = zq - zw; st.w = zw + df; lsum = fmaf(df, df, lsum);
        o4[k4] = st;                                 // plain store
    }

    size_t ob = (size_t)row * 3;
    out4[ob]     = (float)j0;
    out4[ob + 1] = (float)j1;
    out4[ob + 2] = (float)j2;
    atomicAdd(&hist[j0], 1);
    atomicAdd(&hist[j1], 1);
    atomicAdd(&hist[j2], 1);
    return lsum;
}

// ---------------------------------------------------------------------------
// Scorer v3: FOUR ROWS PER LANE + scalar emb loads.
//
// Validated cost model (R5 vs R10): SMEM scalar-operand FMA is the optimal
// operand path (4 B per wave-wide FMA), but R5 exposed ~200 cy of L2 latency
// against only 64 cy of FMA per j -> 4.1x over the 55 us VALU floor (=215 us,
// measured). R10's LDS path moved 67 MB/CU through the DS pipe -> 330 us
// (measured, =12cy/b128 model). Fix: 4 rows per lane -> 256 FMA-instr =
// 512 cy of work per j -> latency exposure (200+512)/512 = 1.39x.
//
// Block = 256 threads = 4 waves; wave w = split w (readfirstlane -> provably
// uniform j -> s_load path, the R1 lesson). Lane l owns rows rbase+l+64q,
// q=0..3 (zr 4x64 = 256 VGPR, 1 wave/SIMD, under the 450 no-spill line).
// Four independent acc chains = perfect ILP. Split triples merge through LDS
// in ascending split order (identical tie semantics); wave w runs the
// epilogue for its q=w rows with compile-time zr selection.
//
// Bit-exactness: per-(row,j) sequential-k fmaf chain, A/Bj terms, insert
// order (ascending j within split, ascending split at merge), epilogue ops,
// and the 64-consecutive-row per-wave lsum reduce are all identical to the
// verified R5 kernel.
// ---------------------------------------------------------------------------
__global__ __launch_bounds__(256, 1) void score_kernel(const float* __restrict__ z,
                                                       const float* __restrict__ emb,
                                                       const float* __restrict__ B,
                                                       float* __restrict__ out0,
                                                       float* __restrict__ out3f,
                                                       float* __restrict__ out4,
                                                       int* __restrict__ hist,
                                                       float* __restrict__ lossAcc) {
    __shared__ float sD[SPLITS][4][64][3];    // [split][q][lane][u]
    __shared__ int   sI[SPLITS][4][64][3];

    int t = threadIdx.x;
    int l = t & 63;
    int w = __builtin_amdgcn_readfirstlane(t >> 6);   // wave id = split, uniform
    int rbase = blockIdx.x * 256;

    float zr0[64], zr1[64], zr2[64], zr3[64];
    load_row(z, rbase + l,       zr0);  float A0 = tree_sum64_sq(zr0);
    load_row(z, rbase + l + 64,  zr1);  float A1 = tree_sum64_sq(zr1);
    load_row(z, rbase + l + 128, zr2);  float A2 = tree_sum64_sq(zr2);
    load_row(z, rbase + l + 192, zr3);  float A3 = tree_sum64_sq(zr3);

    float tv[4][3];
    int   ti[4][3];
#pragma unroll
    for (int q = 0; q < 4; ++q) {
        tv[q][0] = tv[q][1] = tv[q][2] = 3.402823466e38f;
        ti[q][0] = ti[q][1] = ti[q][2] = 0;
    }

    int jbase = w * JS;
    for (int jj = 0; jj < JS; ++jj) {
        int j = jbase + jj;                   // uniform -> scalar loads
        const float4* e4 = (const float4*)(emb + (size_t)j * 64);
        float Bj = B[j];                      // uniform -> scalar load
        float acc0 = 0.0f, acc1 = 0.0f, acc2 = 0.0f, acc3 = 0.0f;
#pragma unroll
        for (int k4 = 0; k4 < 16; ++k4) {
            float4 e = e4[k4];                // uniform -> s_load_dwordx16 path
            acc0 = fmaf(zr0[4 * k4],     e.x, acc0);
            acc1 = fmaf(zr1[4 * k4],     e.x, acc1);
            acc2 = fmaf(zr2[4 * k4],     e.x, acc2);
            acc3 = fmaf(zr3[4 * k4],     e.x, acc3);
            acc0 = fmaf(zr0[4 * k4 + 1], e.y, acc0);
            acc1 = fmaf(zr1[4 * k4 + 1], e.y, acc1);
            acc2 = fmaf(zr2[4 * k4 + 1], e.y, acc2);
            acc3 = fmaf(zr3[4 * k4 + 1], e.y, acc3);
            acc0 = fmaf(zr0[4 * k4 + 2], e.z, acc0);
            acc1 = fmaf(zr1[4 * k4 + 2], e.z, acc1);
            acc2 = fmaf(zr2[4 * k4 + 2], e.z, acc2);
            acc3 = fmaf(zr3[4 * k4 + 2], e.z, acc3);
            acc0 = fmaf(zr0[4 * k4 + 3], e.w, acc0);
            acc1 = fmaf(zr1[4 * k4 + 3], e.w, acc1);
            acc2 = fmaf(zr2[4 * k4 + 3], e.w, acc2);
            acc3 = fmaf(zr3[4 * k4 + 3], e.w, acc3);
        }
        // per-row d with the exact same expression as all passing rounds
        float d0 = (A0 + Bj) - 2.0f * acc0;
        float d1 = (A1 + Bj) - 2.0f * acc1;
        float d2 = (A2 + Bj) - 2.0f * acc2;
        float d3 = (A3 + Bj) - 2.0f * acc3;
        top3_insert(d0, j, tv[0][0], tv[0][1], tv[0][2], ti[0][0], ti[0][1], ti[0][2]);
        top3_insert(d1, j, tv[1][0], tv[1][1], tv[1][2], ti[1][0], ti[1][1], ti[1][2]);
        top3_insert(d2, j, tv[2][0], tv[2][1], tv[2][2], ti[2][0], ti[2][1], ti[2][2]);
        top3_insert(d3, j, tv[3][0], tv[3][1], tv[3][2], ti[3][0], ti[3][1], ti[3][2]);
    }

#pragma unroll
    for (int q = 0; q < 4; ++q)
#pragma unroll
        for (int u = 0; u < 3; ++u) {
            sD[w][q][l][u] = tv[q][u];
            sI[w][q][l][u] = ti[q][u];
        }
    __syncthreads();

    // merge 4 splits for row rbase + w*64 + l (q = w), ascending split order
    float m0 = 3.402823466e38f, m1 = 3.402823466e38f, m2 = 3.402823466e38f;
    int j0 = 0, j1 = 0, j2 = 0;
#pragma unroll
    for (int s = 0; s < SPLITS; ++s)
#pragma unroll
        for (int u = 0; u < 3; ++u)
            top3_insert(sD[s][w][l][u], sI[s][w][l][u], m0, m1, m2, j0, j1, j2);

    int row = rbase + w * 64 + l;
    float lsum;
    if      (w == 0) lsum = epilogue_row(zr0, row, j0, j1, j2, emb, out0, out3f, out4, hist);
    else if (w == 1) lsum = epilogue_row(zr1, row, j0, j1, j2, emb, out0, out3f, out4, hist);
    else if (w == 2) lsum = epilogue_row(zr2, row, j0, j1, j2, emb, out0, out3f, out4, hist);
    else             lsum = epilogue_row(zr3, row, j0, j1, j2, emb, out0, out3f, out4, hist);

    // wave-level reduce of loss partial, one atomic per wave (1024 total,
    // 64 consecutive rows per wave — same shape as all passing rounds)
#pragma unroll
    for (int off = 32; off >= 1; off >>= 1) lsum += __shfl_down(lsum, off);
    if (l == 0) atomicAdd(lossAcc, lsum);
}

// ---------------------------------------------------------------------------
// Perplexity from histogram + loss finalize (unchanged).
// ---------------------------------------------------------------------------
__global__ __launch_bounds__(256) void finalize_kernel(const int* __restrict__ hist,
                                                       const float* __restrict__ lossAcc,
                                                       float* __restrict__ out1,
                                                       float* __restrict__ out2) {
    __shared__ float red[256];
    int t = threadIdx.x;
    float local = 0.0f;
    for (int b = t; b < CB; b += 256) {
        float em = (float)hist[b] / 196608.0f;
        local += em * logf(em + 1e-10f);
    }
    red[t] = local;
    __syncthreads();
    for (int s = 128; s >= 1; s >>= 1) {
        if (t < s) red[t] += red[t + s];
        __syncthreads();
    }
    if (t == 0) {
        *out2 = expf(-red[0]);
        float m = *lossAcc / 4194304.0f;
        *out1 = 0.25f * m + m;     // BETA_C*mse + mse
    }
}

extern "C" void kernel_launch(void* const* d_in, const int* in_sizes, int n_in,
                              void* d_out, int out_size, void* d_ws, size_t ws_size,
                              hipStream_t stream) {
    const float* z   = (const float*)d_in[0];   // [16,64,64,64] -> 65536 x 64
    const float* emb = (const float*)d_in[1];   // [1024, 64]

    float* out  = (float*)d_out;
    float* out0 = out;                                    // z_q_st  4194304
    float* out1 = out + 4194304;                          // loss    1
    float* out2 = out + 4194305;                          // perplexity 1
    float* out3 = out + 4194306;                          // encodings 201326592
    float* out4 = out + 4194306 + 201326592ll;            // topk_idx (as float) 196608

    int*   hist    = (int*)d_ws;                          // 1024 ints @ 0
    float* lossAcc = (float*)((char*)d_ws + 4096);        // 1 float
    float* B       = (float*)((char*)d_ws + 8192);        // 1024 floats

    prep_kernel<<<4, 256, 0, stream>>>(emb, B, hist, lossAcc);
    // 805 MB zero fill at the measured pure-write wall (~2.5 TB/s; 5
    // different arrangements all hit it). Stream order guarantees
    // zeros-before-ones.
    hipMemsetAsync(out3, 0, (size_t)N_ROWS * 3 * CB * sizeof(float), stream);
    score_kernel<<<N_ROWS / 256, 256, 0, stream>>>(z, emb, B, out0, out3, out4,
                                                   hist, lossAcc);
    finalize_kernel<<<1, 256, 0, stream>>>(hist, lossAcc, out1, out2);
}